// Round 7
// baseline (198.140 us; speedup 1.0000x reference)
//
#include <hip/hip_runtime.h>

#define NEG_SLOPE 0.2f

constexpr int N_NODES = 50000;
constexpr int TPB = 256;
constexpr int BSH = 7;                      // 128 nodes per bucket
constexpr int NB = (N_NODES + 127) >> BSH;  // 391 buckets
constexpr int SCAT_CHUNK = 8192;

// ---------------------------------------------------------------------------
// Tiny zero kernel: replaces hipMemsetAsync (which becomes a ~40us blit node
// inside a captured graph for small fills).
// ---------------------------------------------------------------------------
__global__ void zero_ints(int* __restrict__ p, int n) {
  int i = blockIdx.x * blockDim.x + threadIdx.x;
  if (i < n) p[i] = 0;
}

// ---------------------------------------------------------------------------
// One-shot W transpose: Wt[k4*OUTD + c] = float4(W[4k4..4k4+3][c]).
// ---------------------------------------------------------------------------
__global__ void transpose_w4(const float* __restrict__ W,
                             float4* __restrict__ Wt, int K, int OUTD) {
  int i = blockIdx.x * blockDim.x + threadIdx.x;
  if (i >= (K / 4) * OUTD) return;
  int k4 = i / OUTD, c = i % OUTD;
  Wt[i] = make_float4(W[(4 * k4 + 0) * OUTD + c], W[(4 * k4 + 1) * OUTD + c],
                      W[(4 * k4 + 2) * OUTD + c], W[(4 * k4 + 3) * OUTD + c]);
}

// ---------------------------------------------------------------------------
// GEMM + fused alpha epilogue. Wave-private double-buffered LDS pipeline,
// zero block barriers (no vmcnt(0) drain). See R4 notes.
// ---------------------------------------------------------------------------
template <int K, int OUTD>
__global__ __launch_bounds__(TPB) void gemm_alpha(
    const float* __restrict__ X, const float4* __restrict__ Wt,
    const float* __restrict__ avec_src, const float* __restrict__ avec_dst,
    float* __restrict__ Hout, float* __restrict__ as_out,
    float* __restrict__ ad_out, int n) {
  constexpr int BK = 16;         // k per tile step
  constexpr int NT = K / BK;     // tile steps
  constexpr int CT = OUTD / 2;   // col-threads (each owns cols c, c+CT)
  constexpr int RG = 64 / CT;    // row groups per wave
  constexpr int RPT = 16 / RG;   // rows per thread
  constexpr int WPB = TPB / 64;  // waves per block
  __shared__ float xs[WPB][2][16][BK + 4];  // row stride 20 floats (80B)

  const int t = threadIdx.x;
  const int wid = t >> 6;
  const int lane = t & 63;
  const int waveRow0 = blockIdx.x * (WPB * 16) + wid * 16;

  // staging ids: lane -> (row, k-quad); 16 rows x 4 quads = 64 lanes
  const int srow = lane >> 2;
  const int skq = lane & 3;
  const float* srcRow = X + (size_t)min(waveRow0 + srow, n - 1) * K + skq * 4;

  // compute ids
  const int c = lane % CT;
  const int rg = lane / CT;
  const int r0 = rg * RPT;

  const float a_s0 = avec_src[c], a_s1 = avec_src[c + CT];
  const float a_d0 = avec_dst[c], a_d1 = avec_dst[c + CT];

  float4 g = *(const float4*)srcRow;  // tile 0
  *(float4*)&xs[wid][0][srow][skq * 4] = g;

  float acc[RPT][2];
#pragma unroll
  for (int i = 0; i < RPT; ++i) acc[i][0] = acc[i][1] = 0.f;

  for (int tile = 0;;) {
    if (tile + 1 < NT)
      g = *(const float4*)(srcRow + (size_t)(tile + 1) * BK);  // prefetch
    const int buf = tile & 1;
#pragma unroll
    for (int kq = 0; kq < BK / 4; ++kq) {
      const int kqg = tile * (BK / 4) + kq;
      const float4 w0 = Wt[(size_t)kqg * OUTD + c];
      const float4 w1 = Wt[(size_t)kqg * OUTD + c + CT];
#pragma unroll
      for (int i = 0; i < RPT; ++i) {
        const float4 xv = *(const float4*)&xs[wid][buf][r0 + i][kq * 4];
        acc[i][0] = fmaf(xv.x, w0.x, acc[i][0]);
        acc[i][1] = fmaf(xv.x, w1.x, acc[i][1]);
        acc[i][0] = fmaf(xv.y, w0.y, acc[i][0]);
        acc[i][1] = fmaf(xv.y, w1.y, acc[i][1]);
        acc[i][0] = fmaf(xv.z, w0.z, acc[i][0]);
        acc[i][1] = fmaf(xv.z, w1.z, acc[i][1]);
        acc[i][0] = fmaf(xv.w, w0.w, acc[i][0]);
        acc[i][1] = fmaf(xv.w, w1.w, acc[i][1]);
      }
    }
    if (++tile == NT) break;
    *(float4*)&xs[wid][tile & 1][srow][skq * 4] = g;  // wave-private
  }

#pragma unroll
  for (int i = 0; i < RPT; ++i) {
    const int r = waveRow0 + r0 + i;
    if (r < n) {  // uniform within the CT-lane group
      Hout[(size_t)r * OUTD + c] = acc[i][0];
      Hout[(size_t)r * OUTD + c + CT] = acc[i][1];
      float vs = acc[i][0] * a_s0 + acc[i][1] * a_s1;
      float vd = acc[i][0] * a_d0 + acc[i][1] * a_d1;
#pragma unroll
      for (int m = CT / 2; m >= 1; m >>= 1) {
        vs += __shfl_xor(vs, m);
        vd += __shfl_xor(vd, m);
      }
      if (c == 0) {
        as_out[r] = vs;
        ad_out[r] = vd;
      }
    }
  }
}

// ---------------------------------------------------------------------------
// Bucketed CSR-by-dst build (see R5 notes).
// ---------------------------------------------------------------------------
__global__ void bucket_hist(const int* __restrict__ edst, int E,
                            int* __restrict__ pairCnt) {
  __shared__ int h[NB];
  for (int i = threadIdx.x; i < NB; i += blockDim.x) h[i] = 0;
  __syncthreads();
  for (int i = blockIdx.x * blockDim.x + threadIdx.x; i < E;
       i += gridDim.x * blockDim.x)
    atomicAdd(&h[edst[i] >> BSH], 1);
  __syncthreads();
  for (int i = threadIdx.x; i < NB; i += blockDim.x)
    if (h[i]) atomicAdd(&pairCnt[i], h[i]);
}

// single block, 512 threads: scan bucket counts -> segment offsets
__global__ void bucket_scan(const int* __restrict__ pairCnt,
                            int* __restrict__ pairOff,
                            int* __restrict__ pairCursor,
                            int* __restrict__ csrOff, int N) {
  __shared__ int a[512], b[512];
  const int t = threadIdx.x;
  const int pc = (t < NB) ? pairCnt[t] : 0;
  const int nodes = (t < NB) ? min(128, N - (t << BSH)) : 0;
  a[t] = pc;
  b[t] = pc + nodes;
  __syncthreads();
  for (int off = 1; off < 512; off <<= 1) {
    int av = (t >= off) ? a[t - off] : 0;
    int bv = (t >= off) ? b[t - off] : 0;
    __syncthreads();
    a[t] += av;
    b[t] += bv;
    __syncthreads();
  }
  if (t < NB) {
    const int pe = a[t] - pc;  // exclusive
    pairOff[t] = pe;
    pairCursor[t] = pe;
    csrOff[t] = b[t] - (pc + nodes);
  }
  if (t == 0) {
    pairOff[NB] = a[511];
    csrOff[NB] = b[511];
  }
}

__global__ void bucket_scatter(const int* __restrict__ esrc,
                               const int* __restrict__ edst, int E,
                               int* __restrict__ pairCursor,
                               unsigned* __restrict__ stage) {
  __shared__ int h[NB], baseA[NB];
  const int base0 = blockIdx.x * SCAT_CHUNK;
  const int lim = min(E, base0 + SCAT_CHUNK);
  for (int i = threadIdx.x; i < NB; i += blockDim.x) h[i] = 0;
  __syncthreads();
  for (int i = base0 + threadIdx.x; i < lim; i += blockDim.x)
    atomicAdd(&h[edst[i] >> BSH], 1);
  __syncthreads();
  for (int i = threadIdx.x; i < NB; i += blockDim.x) {
    const int c = h[i];
    baseA[i] = c ? atomicAdd(&pairCursor[i], c) : 0;
  }
  __syncthreads();
  for (int i = threadIdx.x; i < NB; i += blockDim.x) h[i] = 0;
  __syncthreads();
  for (int i = base0 + threadIdx.x; i < lim; i += blockDim.x) {
    const int d = edst[i];
    const int s = esrc[i];
    const int bkt = d >> BSH;
    const int pos = baseA[bkt] + atomicAdd(&h[bkt], 1);
    stage[pos] = ((unsigned)(d & 127) << 16) | (unsigned)s;
  }
}

// one block per bucket: LDS count -> LDS scan -> rowoff + self + psrc scatter
__global__ void build_csr(const unsigned* __restrict__ stage,
                          const int* __restrict__ pairOff,
                          const int* __restrict__ csrOff, int N,
                          int* __restrict__ rowoff, int* __restrict__ psrc) {
  __shared__ int cnt[128], excl[128];
  const int b = blockIdx.x, t = threadIdx.x;
  const int n0 = b << BSH;
  const int nn = min(128, N - n0);
  if (t < 128) cnt[t] = (t < nn) ? 1 : 0;  // self loop pre-counted
  __syncthreads();
  const int pb = pairOff[b], pe = pairOff[b + 1];
  for (int k = pb + t; k < pe; k += blockDim.x)
    atomicAdd(&cnt[stage[k] >> 16], 1);
  __syncthreads();
  if (t < 128) excl[t] = cnt[t];
  __syncthreads();
  for (int off = 1; off < 128; off <<= 1) {
    int v = (t < 128 && t >= off) ? excl[t - off] : 0;
    __syncthreads();
    if (t < 128) excl[t] += v;
    __syncthreads();
  }
  const int cb = csrOff[b];
  if (t < 128) {
    const int ex = excl[t] - cnt[t];  // exclusive
    if (t < nn) {
      rowoff[n0 + t] = cb + ex;
      psrc[cb + ex] = n0 + t;  // self edge first
    }
    cnt[t] = ex + 1;  // cursor (self consumed one slot)
  }
  if (b == 0 && t == 0) rowoff[N] = csrOff[NB];
  __syncthreads();
  for (int k = pb + t; k < pe; k += blockDim.x) {
    const unsigned p = stage[k];
    const int ld = p >> 16;
    const int s = p & 0xFFFF;
    const int pos = cb + atomicAdd(&cnt[ld], 1);
    psrc[pos] = s;
  }
}

// ---------------------------------------------------------------------------
// GAT aggregation: one wave per destination node, single-pass online softmax.
// float4 H-row gathers: LPE = D/4 lanes per edge, EPS = 64/LPE edges per
// step (4 for D=64, 8 for D=32). Edge-phase partials folded with shfl_xor.
// ---------------------------------------------------------------------------
template <int D>
__global__ __launch_bounds__(TPB) void gat_aggregate(
    const float* __restrict__ Hf, const float* __restrict__ as,
    const float* __restrict__ ad, const int* __restrict__ rowoff,
    const int* __restrict__ psrc, int n, const float* __restrict__ bias,
    float* __restrict__ out, int doRelu) {
  constexpr int LPE = D / 4;     // lanes per edge (float4 each)
  constexpr int EPS = 64 / LPE;  // edges per step
  constexpr int WPB = TPB / 64;  // waves per block
  __shared__ float2 wsP[WPB][64];

  const int wave = (blockIdx.x * blockDim.x + threadIdx.x) >> 6;
  const int wid = threadIdx.x >> 6;
  const int lane = threadIdx.x & 63;
  if (wave >= n) return;
  const int i = wave;
  const int beg = rowoff[i];
  const int end = rowoff[i + 1];
  const float adi = ad[i];

  const int p = lane / LPE;          // edge phase within a step
  const int fl4 = (lane % LPE) * 4;  // feature quad base

  float m = -1e30f, denom = 0.f;
  float4 acc = make_float4(0.f, 0.f, 0.f, 0.f);

  for (int c = beg; c < end; c += 64) {
    const int k = c + lane;
    const bool valid = (k < end);
    int s = 0;
    float e = -1e30f;
    if (valid) {
      s = psrc[k];
      e = as[s] + adi;
      e = (e > 0.f) ? e : e * NEG_SLOPE;
    }
    // chunk max over the wave
    float cm = e;
#pragma unroll
    for (int mm = 32; mm >= 1; mm >>= 1) cm = fmaxf(cm, __shfl_xor(cm, mm));
    const float nm = fmaxf(m, cm);
    const float scale = __expf(m - nm);  // first chunk: exp(-inf) = 0
    const float w = valid ? __expf(e - nm) : 0.f;
    float ws = w;
#pragma unroll
    for (int mm = 32; mm >= 1; mm >>= 1) ws += __shfl_xor(ws, mm);
    denom = denom * scale + ws;
    acc.x *= scale;
    acc.y *= scale;
    acc.z *= scale;
    acc.w *= scale;
    m = nm;

    wsP[wid][lane] = make_float2(w, __int_as_float(s));  // park (w, src)

    const int cnt = min(64, end - c);
    const int nsteps = (cnt + EPS - 1) / EPS;
#pragma unroll 4
    for (int j = 0; j < nsteps; ++j) {
      const float2 p2 = wsP[wid][j * EPS + p];
      const float wj = p2.x;
      const int sj = __float_as_int(p2.y);
      const float4 hv = *(const float4*)(Hf + (size_t)sj * D + fl4);
      acc.x = fmaf(wj, hv.x, acc.x);
      acc.y = fmaf(wj, hv.y, acc.y);
      acc.z = fmaf(wj, hv.z, acc.z);
      acc.w = fmaf(wj, hv.w, acc.w);
    }
  }
  // fold edge-phase partials
#pragma unroll
  for (int mm = LPE; mm < 64; mm <<= 1) {
    acc.x += __shfl_xor(acc.x, mm);
    acc.y += __shfl_xor(acc.y, mm);
    acc.z += __shfl_xor(acc.z, mm);
    acc.w += __shfl_xor(acc.w, mm);
  }
  if (lane < LPE) {
    const float4 bv = *(const float4*)(bias + fl4);
    float4 o;
    o.x = acc.x / denom + bv.x;
    o.y = acc.y / denom + bv.y;
    o.z = acc.z / denom + bv.z;
    o.w = acc.w / denom + bv.w;
    if (doRelu) {
      o.x = fmaxf(o.x, 0.f);
      o.y = fmaxf(o.y, 0.f);
      o.z = fmaxf(o.z, 0.f);
      o.w = fmaxf(o.w, 0.f);
    }
    *(float4*)(out + (size_t)i * D + fl4) = o;
  }
}

// ---------------------------------------------------------------------------
// Decode: logits[g] = dot(z[src], z[dst]) over 32 dims.
// Wave = 8 edges. Lanes 0-15 cooperatively load the wave's 16 indices
// (2 coalesced bursts), distributed by shfl -> no redundant index loads.
// 8 lanes per edge, float4 per lane (coalesced 128B per row).
// ---------------------------------------------------------------------------
__device__ __forceinline__ int loadS(const int* __restrict__ pos,
                                     const int* __restrict__ neg, int ED,
                                     int g) {
  return (g < ED) ? pos[g] : neg[g - ED];
}
__device__ __forceinline__ int loadD(const int* __restrict__ pos,
                                     const int* __restrict__ neg, int ED,
                                     int g) {
  return (g < ED) ? pos[ED + g] : neg[ED + (g - ED)];
}

__global__ __launch_bounds__(TPB) void decode_kernel(
    const float* __restrict__ z, const int* __restrict__ pos,
    const int* __restrict__ neg, int ED, float* __restrict__ out) {
  const int wv = (blockIdx.x * blockDim.x + threadIdx.x) >> 6;
  const int lane = threadIdx.x & 63;
  const int g0 = wv * 8;
  const int NG = 2 * ED;
  if (g0 >= NG) return;

  int my = 0;
  if (lane < 16) {
    const int g = g0 + (lane & 7);
    if (g < NG) my = (lane < 8) ? loadS(pos, neg, ED, g) : loadD(pos, neg, ED, g);
  }
  const int e = lane >> 3;
  const int fl = lane & 7;
  const int s = __shfl(my, e);
  const int d = __shfl(my, 8 + e);
  const int g = g0 + e;
  if (g >= NG) return;

  const float4 a = ((const float4*)(z + (size_t)s * 32))[fl];
  const float4 b = ((const float4*)(z + (size_t)d * 32))[fl];
  float v = a.x * b.x + a.y * b.y + a.z * b.z + a.w * b.w;
#pragma unroll
  for (int mm = 4; mm >= 1; mm >>= 1) v += __shfl_xor(v, mm);
  if (fl == 0) out[g] = v;
}

// ---------------------------------------------------------------------------
extern "C" void kernel_launch(void* const* d_in, const int* in_sizes, int n_in,
                              void* d_out, int out_size, void* d_ws,
                              size_t ws_size, hipStream_t stream) {
  const int N = N_NODES;
  const float* x = (const float*)d_in[0];
  const int* ei = (const int*)d_in[1];
  const int* pe = (const int*)d_in[2];
  const int* ne = (const int*)d_in[3];
  const float* W1 = (const float*)d_in[4];
  const float* a_src1 = (const float*)d_in[5];
  const float* a_dst1 = (const float*)d_in[6];
  const float* b1 = (const float*)d_in[7];
  const float* W2 = (const float*)d_in[8];
  const float* a_src2 = (const float*)d_in[9];
  const float* a_dst2 = (const float*)d_in[10];
  const float* b2 = (const float*)d_in[11];
  float* out = (float*)d_out;

  const int E = in_sizes[1] / 2;
  const int ED = in_sizes[2] / 2;
  const int* esrc = ei;
  const int* edst = ei + E;

  // workspace carve-out (256B aligned)
  char* base = (char*)d_ws;
  size_t off = 0;
  auto alloc = [&](size_t bytes) {
    char* p = base + off;
    off = (off + bytes + 255) & ~(size_t)255;
    return p;
  };
  float* A = (float*)alloc((size_t)N * 64 * 4);  // h1, later h2
  float* B = (float*)alloc((size_t)N * 64 * 4);  // out1, later z
  float* as1 = (float*)alloc((size_t)N * 4);
  float* ad1 = (float*)alloc((size_t)N * 4);
  float* as2 = (float*)alloc((size_t)N * 4);
  float* ad2 = (float*)alloc((size_t)N * 4);
  int* rowoff = (int*)alloc((size_t)(N + 1) * 4);
  int* psrc = (int*)alloc((size_t)(E + N) * 4);
  unsigned* stage = (unsigned*)alloc((size_t)E * 4);
  int* pairCnt = (int*)alloc((size_t)NB * 4);
  int* pairOff = (int*)alloc((size_t)(NB + 1) * 4);
  int* pairCursor = (int*)alloc((size_t)NB * 4);
  int* csrOff = (int*)alloc((size_t)(NB + 1) * 4);
  float4* Wt1 = (float4*)alloc((size_t)(128 / 4) * 64 * 16);
  float4* Wt2 = (float4*)alloc((size_t)(64 / 4) * 32 * 16);

  // --- W pre-transpose + pairCnt zero (tiny, once) ---
  zero_ints<<<(NB + 511) / 512, 512, 0, stream>>>(pairCnt, NB);
  transpose_w4<<<(32 * 64 + TPB - 1) / TPB, TPB, 0, stream>>>(W1, Wt1, 128, 64);
  transpose_w4<<<(16 * 32 + TPB - 1) / TPB, TPB, 0, stream>>>(W2, Wt2, 64, 32);

  // --- bucketed CSR build (shared by both layers) ---
  bucket_hist<<<256, TPB, 0, stream>>>(edst, E, pairCnt);
  bucket_scan<<<1, 512, 0, stream>>>(pairCnt, pairOff, pairCursor, csrOff, N);
  bucket_scatter<<<(E + SCAT_CHUNK - 1) / SCAT_CHUNK, TPB, 0, stream>>>(
      esrc, edst, E, pairCursor, stage);
  build_csr<<<NB, TPB, 0, stream>>>(stage, pairOff, csrOff, N, rowoff, psrc);

  // --- layer 1: h1 = x@W1 (+alpha dots), aggregate (+b1, relu) ---
  gemm_alpha<128, 64><<<(N + 63) / 64, TPB, 0, stream>>>(x, Wt1, a_src1,
                                                         a_dst1, A, as1, ad1, N);
  gat_aggregate<64><<<(N + 3) / 4, TPB, 0, stream>>>(A, as1, ad1, rowoff, psrc,
                                                     N, b1, B, 1);

  // --- layer 2: h2 = out1@W2 (+alpha dots), aggregate (+b2) ---
  gemm_alpha<64, 32><<<(N + 63) / 64, TPB, 0, stream>>>(B, Wt2, a_src2, a_dst2,
                                                        A, as2, ad2, N);
  gat_aggregate<32><<<(N + 3) / 4, TPB, 0, stream>>>(A, as2, ad2, rowoff, psrc,
                                                     N, b2, B, 0);

  // --- decode ---
  const long long decThreads = 2LL * ED * 8;
  decode_kernel<<<(int)((decThreads + TPB - 1) / TPB), TPB, 0, stream>>>(
      B, pe, ne, ED, out);
}

// Round 8
// 178.147 us; speedup vs baseline: 1.1122x; 1.1122x over previous
//
#include <hip/hip_runtime.h>

#define NEG_SLOPE 0.2f

constexpr int N_NODES = 50000;
constexpr int TPB = 256;
constexpr int BSH = 7;                      // 128 nodes per bucket
constexpr int NB = (N_NODES + 127) >> BSH;  // 391 buckets
constexpr int SCAT_CHUNK = 8192;

// bf16 helpers (RNE pack, cheap unpack)
__device__ __forceinline__ unsigned short f2b(float f) {
  unsigned u = __float_as_uint(f);
  return (unsigned short)((u + 0x7FFFu + ((u >> 16) & 1u)) >> 16);
}
__device__ __forceinline__ float b2f(unsigned short b) {
  return __uint_as_float(((unsigned)b) << 16);
}

__global__ void zero_ints(int* __restrict__ p, int n) {
  int i = blockIdx.x * blockDim.x + threadIdx.x;
  if (i < n) p[i] = 0;
}

// ---------------------------------------------------------------------------
// One-shot W transpose: Wt[k4*OUTD + c] = float4(W[4k4..4k4+3][c]).
// ---------------------------------------------------------------------------
__global__ void transpose_w4(const float* __restrict__ W,
                             float4* __restrict__ Wt, int K, int OUTD) {
  int i = blockIdx.x * blockDim.x + threadIdx.x;
  if (i >= (K / 4) * OUTD) return;
  int k4 = i / OUTD, c = i % OUTD;
  Wt[i] = make_float4(W[(4 * k4 + 0) * OUTD + c], W[(4 * k4 + 1) * OUTD + c],
                      W[(4 * k4 + 2) * OUTD + c], W[(4 * k4 + 3) * OUTD + c]);
}

// ---------------------------------------------------------------------------
// GEMM + fused alpha epilogue. Wave-private double-buffered LDS pipeline,
// zero block barriers. Each thread owns ADJACENT cols (2c, 2c+1) and writes
// H as packed bf16 ushort2 (H is consumed only by random gathers -> bf16
// halves gather traffic and fits per-XCD L2). alpha dots from fp32 accs.
// ---------------------------------------------------------------------------
template <int K, int OUTD>
__global__ __launch_bounds__(TPB) void gemm_alpha(
    const float* __restrict__ X, const float4* __restrict__ Wt,
    const float* __restrict__ avec_src, const float* __restrict__ avec_dst,
    unsigned short* __restrict__ Hout, float* __restrict__ as_out,
    float* __restrict__ ad_out, int n) {
  constexpr int BK = 16;         // k per tile step
  constexpr int NT = K / BK;     // tile steps
  constexpr int CT = OUTD / 2;   // col-threads (each owns cols 2c, 2c+1)
  constexpr int RG = 64 / CT;    // row groups per wave
  constexpr int RPT = 16 / RG;   // rows per thread
  constexpr int WPB = TPB / 64;  // waves per block
  __shared__ float xs[WPB][2][16][BK + 4];  // row stride 20 floats (80B)

  const int t = threadIdx.x;
  const int wid = t >> 6;
  const int lane = t & 63;
  const int waveRow0 = blockIdx.x * (WPB * 16) + wid * 16;

  // staging ids: lane -> (row, k-quad); 16 rows x 4 quads = 64 lanes
  const int srow = lane >> 2;
  const int skq = lane & 3;
  const float* srcRow = X + (size_t)min(waveRow0 + srow, n - 1) * K + skq * 4;

  // compute ids
  const int cc = lane % CT;
  const int c0 = 2 * cc;
  const int rg = lane / CT;
  const int r0 = rg * RPT;

  const float a_s0 = avec_src[c0], a_s1 = avec_src[c0 + 1];
  const float a_d0 = avec_dst[c0], a_d1 = avec_dst[c0 + 1];

  float4 g = *(const float4*)srcRow;  // tile 0
  *(float4*)&xs[wid][0][srow][skq * 4] = g;

  float acc[RPT][2];
#pragma unroll
  for (int i = 0; i < RPT; ++i) acc[i][0] = acc[i][1] = 0.f;

  for (int tile = 0;;) {
    if (tile + 1 < NT)
      g = *(const float4*)(srcRow + (size_t)(tile + 1) * BK);  // prefetch
    const int buf = tile & 1;
#pragma unroll
    for (int kq = 0; kq < BK / 4; ++kq) {
      const int kqg = tile * (BK / 4) + kq;
      const float4 w0 = Wt[(size_t)kqg * OUTD + c0];
      const float4 w1 = Wt[(size_t)kqg * OUTD + c0 + 1];
#pragma unroll
      for (int i = 0; i < RPT; ++i) {
        const float4 xv = *(const float4*)&xs[wid][buf][r0 + i][kq * 4];
        acc[i][0] = fmaf(xv.x, w0.x, acc[i][0]);
        acc[i][1] = fmaf(xv.x, w1.x, acc[i][1]);
        acc[i][0] = fmaf(xv.y, w0.y, acc[i][0]);
        acc[i][1] = fmaf(xv.y, w1.y, acc[i][1]);
        acc[i][0] = fmaf(xv.z, w0.z, acc[i][0]);
        acc[i][1] = fmaf(xv.z, w1.z, acc[i][1]);
        acc[i][0] = fmaf(xv.w, w0.w, acc[i][0]);
        acc[i][1] = fmaf(xv.w, w1.w, acc[i][1]);
      }
    }
    if (++tile == NT) break;
    *(float4*)&xs[wid][tile & 1][srow][skq * 4] = g;  // wave-private
  }

#pragma unroll
  for (int i = 0; i < RPT; ++i) {
    const int r = waveRow0 + r0 + i;
    if (r < n) {  // uniform within the CT-lane group
      ushort2 hb;
      hb.x = f2b(acc[i][0]);
      hb.y = f2b(acc[i][1]);
      ((ushort2*)Hout)[(size_t)r * CT + cc] = hb;
      float vs = acc[i][0] * a_s0 + acc[i][1] * a_s1;
      float vd = acc[i][0] * a_d0 + acc[i][1] * a_d1;
#pragma unroll
      for (int m = CT / 2; m >= 1; m >>= 1) {
        vs += __shfl_xor(vs, m);
        vd += __shfl_xor(vd, m);
      }
      if (cc == 0) {
        as_out[r] = vs;
        ad_out[r] = vd;
      }
    }
  }
}

// ---------------------------------------------------------------------------
// Bucketed CSR-by-dst build (see R5 notes).
// ---------------------------------------------------------------------------
__global__ void bucket_hist(const int* __restrict__ edst, int E,
                            int* __restrict__ pairCnt) {
  __shared__ int h[NB];
  for (int i = threadIdx.x; i < NB; i += blockDim.x) h[i] = 0;
  __syncthreads();
  for (int i = blockIdx.x * blockDim.x + threadIdx.x; i < E;
       i += gridDim.x * blockDim.x)
    atomicAdd(&h[edst[i] >> BSH], 1);
  __syncthreads();
  for (int i = threadIdx.x; i < NB; i += blockDim.x)
    if (h[i]) atomicAdd(&pairCnt[i], h[i]);
}

__global__ void bucket_scan(const int* __restrict__ pairCnt,
                            int* __restrict__ pairOff,
                            int* __restrict__ pairCursor,
                            int* __restrict__ csrOff, int N) {
  __shared__ int a[512], b[512];
  const int t = threadIdx.x;
  const int pc = (t < NB) ? pairCnt[t] : 0;
  const int nodes = (t < NB) ? min(128, N - (t << BSH)) : 0;
  a[t] = pc;
  b[t] = pc + nodes;
  __syncthreads();
  for (int off = 1; off < 512; off <<= 1) {
    int av = (t >= off) ? a[t - off] : 0;
    int bv = (t >= off) ? b[t - off] : 0;
    __syncthreads();
    a[t] += av;
    b[t] += bv;
    __syncthreads();
  }
  if (t < NB) {
    const int pe = a[t] - pc;  // exclusive
    pairOff[t] = pe;
    pairCursor[t] = pe;
    csrOff[t] = b[t] - (pc + nodes);
  }
  if (t == 0) {
    pairOff[NB] = a[511];
    csrOff[NB] = b[511];
  }
}

__global__ void bucket_scatter(const int* __restrict__ esrc,
                               const int* __restrict__ edst, int E,
                               int* __restrict__ pairCursor,
                               unsigned* __restrict__ stage) {
  __shared__ int h[NB], baseA[NB];
  const int base0 = blockIdx.x * SCAT_CHUNK;
  const int lim = min(E, base0 + SCAT_CHUNK);
  for (int i = threadIdx.x; i < NB; i += blockDim.x) h[i] = 0;
  __syncthreads();
  for (int i = base0 + threadIdx.x; i < lim; i += blockDim.x)
    atomicAdd(&h[edst[i] >> BSH], 1);
  __syncthreads();
  for (int i = threadIdx.x; i < NB; i += blockDim.x) {
    const int c = h[i];
    baseA[i] = c ? atomicAdd(&pairCursor[i], c) : 0;
  }
  __syncthreads();
  for (int i = threadIdx.x; i < NB; i += blockDim.x) h[i] = 0;
  __syncthreads();
  for (int i = base0 + threadIdx.x; i < lim; i += blockDim.x) {
    const int d = edst[i];
    const int s = esrc[i];
    const int bkt = d >> BSH;
    const int pos = baseA[bkt] + atomicAdd(&h[bkt], 1);
    stage[pos] = ((unsigned)(d & 127) << 16) | (unsigned)s;
  }
}

__global__ void build_csr(const unsigned* __restrict__ stage,
                          const int* __restrict__ pairOff,
                          const int* __restrict__ csrOff, int N,
                          int* __restrict__ rowoff, int* __restrict__ psrc) {
  __shared__ int cnt[128], excl[128];
  const int b = blockIdx.x, t = threadIdx.x;
  const int n0 = b << BSH;
  const int nn = min(128, N - n0);
  if (t < 128) cnt[t] = (t < nn) ? 1 : 0;  // self loop pre-counted
  __syncthreads();
  const int pb = pairOff[b], pe = pairOff[b + 1];
  for (int k = pb + t; k < pe; k += blockDim.x)
    atomicAdd(&cnt[stage[k] >> 16], 1);
  __syncthreads();
  if (t < 128) excl[t] = cnt[t];
  __syncthreads();
  for (int off = 1; off < 128; off <<= 1) {
    int v = (t < 128 && t >= off) ? excl[t - off] : 0;
    __syncthreads();
    if (t < 128) excl[t] += v;
    __syncthreads();
  }
  const int cb = csrOff[b];
  if (t < 128) {
    const int ex = excl[t] - cnt[t];  // exclusive
    if (t < nn) {
      rowoff[n0 + t] = cb + ex;
      psrc[cb + ex] = n0 + t;  // self edge first
    }
    cnt[t] = ex + 1;  // cursor (self consumed one slot)
  }
  if (b == 0 && t == 0) rowoff[N] = csrOff[NB];
  __syncthreads();
  for (int k = pb + t; k < pe; k += blockDim.x) {
    const unsigned p = stage[k];
    const int ld = p >> 16;
    const int s = p & 0xFFFF;
    const int pos = cb + atomicAdd(&cnt[ld], 1);
    psrc[pos] = s;
  }
}

// ---------------------------------------------------------------------------
// GAT aggregation: one wave per destination node, single-pass online softmax.
// H rows gathered as bf16 (ushort4 = 4 feats / lane): LPE = D/4 lanes per
// edge, EPS = 64/LPE edges per step. fp32 accumulation. Output fp32 (layer1)
// or bf16 (layer2 -> z, consumed only by decode gathers).
// ---------------------------------------------------------------------------
template <int D, bool OUT_BF16>
__global__ __launch_bounds__(TPB) void gat_aggregate(
    const unsigned short* __restrict__ Hb, const float* __restrict__ as,
    const float* __restrict__ ad, const int* __restrict__ rowoff,
    const int* __restrict__ psrc, int n, const float* __restrict__ bias,
    float* __restrict__ outF, unsigned short* __restrict__ outB, int doRelu) {
  constexpr int LPE = D / 4;     // lanes per edge (4 bf16 feats each)
  constexpr int EPS = 64 / LPE;  // edges per step
  constexpr int WPB = TPB / 64;  // waves per block
  __shared__ float2 wsP[WPB][64];

  const int wave = (blockIdx.x * blockDim.x + threadIdx.x) >> 6;
  const int wid = threadIdx.x >> 6;
  const int lane = threadIdx.x & 63;
  if (wave >= n) return;
  const int i = wave;
  const int beg = rowoff[i];
  const int end = rowoff[i + 1];
  const float adi = ad[i];

  const int p = lane / LPE;          // edge phase within a step
  const int fl4 = (lane % LPE) * 4;  // feature quad base

  float m = -1e30f, denom = 0.f;
  float4 acc = make_float4(0.f, 0.f, 0.f, 0.f);

  for (int c = beg; c < end; c += 64) {
    const int k = c + lane;
    const bool valid = (k < end);
    int s = 0;
    float e = -1e30f;
    if (valid) {
      s = psrc[k];
      e = as[s] + adi;
      e = (e > 0.f) ? e : e * NEG_SLOPE;
    }
    // chunk max over the wave
    float cm = e;
#pragma unroll
    for (int mm = 32; mm >= 1; mm >>= 1) cm = fmaxf(cm, __shfl_xor(cm, mm));
    const float nm = fmaxf(m, cm);
    const float scale = __expf(m - nm);  // first chunk: exp(-inf) = 0
    const float w = valid ? __expf(e - nm) : 0.f;
    float ws = w;
#pragma unroll
    for (int mm = 32; mm >= 1; mm >>= 1) ws += __shfl_xor(ws, mm);
    denom = denom * scale + ws;
    acc.x *= scale;
    acc.y *= scale;
    acc.z *= scale;
    acc.w *= scale;
    m = nm;

    wsP[wid][lane] = make_float2(w, __int_as_float(s));  // park (w, src)

    const int cnt = min(64, end - c);
    const int nsteps = (cnt + EPS - 1) / EPS;
#pragma unroll 4
    for (int j = 0; j < nsteps; ++j) {
      const float2 p2 = wsP[wid][j * EPS + p];
      const float wj = p2.x;
      const int sj = __float_as_int(p2.y);
      const ushort4 hu = *(const ushort4*)(Hb + (size_t)sj * D + fl4);
      acc.x = fmaf(wj, b2f(hu.x), acc.x);
      acc.y = fmaf(wj, b2f(hu.y), acc.y);
      acc.z = fmaf(wj, b2f(hu.z), acc.z);
      acc.w = fmaf(wj, b2f(hu.w), acc.w);
    }
  }
  // fold edge-phase partials
#pragma unroll
  for (int mm = LPE; mm < 64; mm <<= 1) {
    acc.x += __shfl_xor(acc.x, mm);
    acc.y += __shfl_xor(acc.y, mm);
    acc.z += __shfl_xor(acc.z, mm);
    acc.w += __shfl_xor(acc.w, mm);
  }
  if (lane < LPE) {
    const float4 bv = *(const float4*)(bias + fl4);
    float4 o;
    o.x = acc.x / denom + bv.x;
    o.y = acc.y / denom + bv.y;
    o.z = acc.z / denom + bv.z;
    o.w = acc.w / denom + bv.w;
    if (doRelu) {
      o.x = fmaxf(o.x, 0.f);
      o.y = fmaxf(o.y, 0.f);
      o.z = fmaxf(o.z, 0.f);
      o.w = fmaxf(o.w, 0.f);
    }
    if (OUT_BF16) {
      ushort4 ob;
      ob.x = f2b(o.x);
      ob.y = f2b(o.y);
      ob.z = f2b(o.z);
      ob.w = f2b(o.w);
      *(ushort4*)(outB + (size_t)i * D + fl4) = ob;
    } else {
      *(float4*)(outF + (size_t)i * D + fl4) = o;
    }
  }
}

// ---------------------------------------------------------------------------
// Decode: logits[g] = dot(z[src], z[dst]) over 32 dims, z in bf16 (64B rows,
// fits per-XCD L2). Wave = 8 edges; lanes 0-15 cooperatively load indices.
// 8 lanes per edge, ushort4 (4 feats) per lane.
// ---------------------------------------------------------------------------
__device__ __forceinline__ int loadS(const int* __restrict__ pos,
                                     const int* __restrict__ neg, int ED,
                                     int g) {
  return (g < ED) ? pos[g] : neg[g - ED];
}
__device__ __forceinline__ int loadD(const int* __restrict__ pos,
                                     const int* __restrict__ neg, int ED,
                                     int g) {
  return (g < ED) ? pos[ED + g] : neg[ED + (g - ED)];
}

__global__ __launch_bounds__(TPB) void decode_kernel(
    const unsigned short* __restrict__ zb, const int* __restrict__ pos,
    const int* __restrict__ neg, int ED, float* __restrict__ out) {
  const int wv = (blockIdx.x * blockDim.x + threadIdx.x) >> 6;
  const int lane = threadIdx.x & 63;
  const int g0 = wv * 8;
  const int NG = 2 * ED;
  if (g0 >= NG) return;

  int my = 0;
  if (lane < 16) {
    const int g = g0 + (lane & 7);
    if (g < NG)
      my = (lane < 8) ? loadS(pos, neg, ED, g) : loadD(pos, neg, ED, g);
  }
  const int e = lane >> 3;
  const int fl = lane & 7;
  const int s = __shfl(my, e);
  const int d = __shfl(my, 8 + e);
  const int g = g0 + e;
  if (g >= NG) return;

  const ushort4 a = ((const ushort4*)(zb + (size_t)s * 32))[fl];
  const ushort4 b = ((const ushort4*)(zb + (size_t)d * 32))[fl];
  float v = b2f(a.x) * b2f(b.x) + b2f(a.y) * b2f(b.y) + b2f(a.z) * b2f(b.z) +
            b2f(a.w) * b2f(b.w);
#pragma unroll
  for (int mm = 4; mm >= 1; mm >>= 1) v += __shfl_xor(v, mm);
  if (fl == 0) out[g] = v;
}

// ---------------------------------------------------------------------------
extern "C" void kernel_launch(void* const* d_in, const int* in_sizes, int n_in,
                              void* d_out, int out_size, void* d_ws,
                              size_t ws_size, hipStream_t stream) {
  const int N = N_NODES;
  const float* x = (const float*)d_in[0];
  const int* ei = (const int*)d_in[1];
  const int* pe = (const int*)d_in[2];
  const int* ne = (const int*)d_in[3];
  const float* W1 = (const float*)d_in[4];
  const float* a_src1 = (const float*)d_in[5];
  const float* a_dst1 = (const float*)d_in[6];
  const float* b1 = (const float*)d_in[7];
  const float* W2 = (const float*)d_in[8];
  const float* a_src2 = (const float*)d_in[9];
  const float* a_dst2 = (const float*)d_in[10];
  const float* b2 = (const float*)d_in[11];
  float* out = (float*)d_out;

  const int E = in_sizes[1] / 2;
  const int ED = in_sizes[2] / 2;
  const int* esrc = ei;
  const int* edst = ei + E;

  // workspace carve-out (256B aligned)
  char* base = (char*)d_ws;
  size_t off = 0;
  auto alloc = [&](size_t bytes) {
    char* p = base + off;
    off = (off + bytes + 255) & ~(size_t)255;
    return p;
  };
  unsigned short* h1b = (unsigned short*)alloc((size_t)N * 64 * 2);  // bf16 h1
  float* out1 = (float*)alloc((size_t)N * 64 * 4);                   // fp32
  unsigned short* h2b = (unsigned short*)alloc((size_t)N * 32 * 2);  // bf16 h2
  unsigned short* zb = (unsigned short*)alloc((size_t)N * 32 * 2);   // bf16 z
  float* as1 = (float*)alloc((size_t)N * 4);
  float* ad1 = (float*)alloc((size_t)N * 4);
  float* as2 = (float*)alloc((size_t)N * 4);
  float* ad2 = (float*)alloc((size_t)N * 4);
  int* rowoff = (int*)alloc((size_t)(N + 1) * 4);
  int* psrc = (int*)alloc((size_t)(E + N) * 4);
  unsigned* stage = (unsigned*)alloc((size_t)E * 4);
  int* pairCnt = (int*)alloc((size_t)NB * 4);
  int* pairOff = (int*)alloc((size_t)(NB + 1) * 4);
  int* pairCursor = (int*)alloc((size_t)NB * 4);
  int* csrOff = (int*)alloc((size_t)(NB + 1) * 4);
  float4* Wt1 = (float4*)alloc((size_t)(128 / 4) * 64 * 16);
  float4* Wt2 = (float4*)alloc((size_t)(64 / 4) * 32 * 16);

  // --- W pre-transpose + pairCnt zero (tiny, once) ---
  zero_ints<<<(NB + 511) / 512, 512, 0, stream>>>(pairCnt, NB);
  transpose_w4<<<(32 * 64 + TPB - 1) / TPB, TPB, 0, stream>>>(W1, Wt1, 128, 64);
  transpose_w4<<<(16 * 32 + TPB - 1) / TPB, TPB, 0, stream>>>(W2, Wt2, 64, 32);

  // --- bucketed CSR build (shared by both layers) ---
  bucket_hist<<<256, TPB, 0, stream>>>(edst, E, pairCnt);
  bucket_scan<<<1, 512, 0, stream>>>(pairCnt, pairOff, pairCursor, csrOff, N);
  bucket_scatter<<<(E + SCAT_CHUNK - 1) / SCAT_CHUNK, TPB, 0, stream>>>(
      esrc, edst, E, pairCursor, stage);
  build_csr<<<NB, TPB, 0, stream>>>(stage, pairOff, csrOff, N, rowoff, psrc);

  // --- layer 1: h1 = x@W1 (+alpha dots), aggregate (+b1, relu) ---
  gemm_alpha<128, 64><<<(N + 63) / 64, TPB, 0, stream>>>(
      x, Wt1, a_src1, a_dst1, h1b, as1, ad1, N);
  gat_aggregate<64, false><<<(N + 3) / 4, TPB, 0, stream>>>(
      h1b, as1, ad1, rowoff, psrc, N, b1, out1, nullptr, 1);

  // --- layer 2: h2 = out1@W2 (+alpha dots), aggregate (+b2) ---
  gemm_alpha<64, 32><<<(N + 63) / 64, TPB, 0, stream>>>(
      out1, Wt2, a_src2, a_dst2, h2b, as2, ad2, N);
  gat_aggregate<32, true><<<(N + 3) / 4, TPB, 0, stream>>>(
      h2b, as2, ad2, rowoff, psrc, N, b2, nullptr, zb, 0);

  // --- decode ---
  const long long decThreads = 2LL * ED * 8;
  decode_kernel<<<(int)((decThreads + TPB - 1) / TPB), TPB, 0, stream>>>(
      zb, pe, ne, ED, out);
}